// Round 5
// baseline (26274.561 us; speedup 1.0000x reference)
//
#include <hip/hip_runtime.h>
#include <hip/hip_fp16.h>

typedef float f32x4 __attribute__((ext_vector_type(4)));

#define EMB   300
#define HID   300
#define G4    1200
#define TAGS  64
#define BB    64
#define TT    512
#define MM    (BB*TT)
#define NBLK  256
#define NTH   704
#define UQ    19            // uint4 (8 fp16) per dot thread
#define UU    76            // uints per dot thread

__device__ __forceinline__ float sigm(float x) {
    return 1.0f / (1.0f + __expf(-x));
}
__device__ __forceinline__ float tanh_fast(float x) {
    float e = __expf(-2.0f * fabsf(x));
    float r = (1.0f - e) / (1.0f + e);
    return copysignf(r, x);
}

// ---------------- K1: xg = emb[tokens] @ W + bias, stored fp16 --------------
__global__ __launch_bounds__(256)
void k1_xg(const int* __restrict__ tokens, const int* __restrict__ seqlen,
           const float* __restrict__ emb,
           const float* __restrict__ Wf, const float* __restrict__ bf,
           const float* __restrict__ Wb, const float* __restrict__ bb,
           __half* __restrict__ xgf, __half* __restrict__ xgb)
{
    const int z = blockIdx.z;
    const float* __restrict__ W    = z ? Wb : Wf;
    const float* __restrict__ bias = z ? bb : bf;
    __half* __restrict__ out       = z ? xgb : xgf;

    const int row0 = blockIdx.x * 64;
    const int b    = row0 >> 9;
    const int t0   = row0 & 511;
    if (t0 >= seqlen[b]) return;       // whole strip masked -> never consumed

    const int n0 = blockIdx.y * 64;

    __shared__ __align__(16) float As[20][64];
    __shared__ __align__(16) float Bs[20][64];
    __shared__ int toks[64];

    const int tid = threadIdx.x;
    if (tid < 64) toks[tid] = tokens[row0 + tid];
    __syncthreads();

    const int tx = tid & 15, ty = tid >> 4;
    const int rm = ty * 4,   cn = tx * 4;

    float acc[4][4] = {{0.f}};

    const int ar  = tid & 63;
    const int ak0 = (tid >> 6) * 5;

    for (int kc = 0; kc < EMB; kc += 20) {
        const float* arow = emb + (size_t)toks[ar] * EMB + (kc + ak0);
        #pragma unroll
        for (int u = 0; u < 5; ++u) As[ak0 + u][ar] = arow[u];
        const int colb = n0 + ar;
        #pragma unroll
        for (int u = 0; u < 5; ++u) {
            float v = 0.f;
            if (colb < G4) v = W[(size_t)(kc + ak0 + u) * G4 + colb];
            Bs[ak0 + u][ar] = v;
        }
        __syncthreads();
        #pragma unroll
        for (int k = 0; k < 20; ++k) {
            f32x4 av = *(const f32x4*)&As[k][rm];
            f32x4 bv = *(const f32x4*)&Bs[k][cn];
            #pragma unroll
            for (int i = 0; i < 4; ++i)
                #pragma unroll
                for (int j = 0; j < 4; ++j)
                    acc[i][j] = fmaf(av[i], bv[j], acc[i][j]);
        }
        __syncthreads();
    }
    #pragma unroll
    for (int i = 0; i < 4; ++i) {
        const int row = row0 + rm + i;
        #pragma unroll
        for (int j = 0; j < 4; ++j) {
            const int col = n0 + cn + j;
            if (col < G4)
                out[(size_t)row * G4 + col] = __float2half(acc[i][j] + bias[col]);
        }
    }
}

// ---------------- kU: pack per-(dir,part,thread) U register images ----------
// Upp uint idx = ((dir*4+part)*600 + t)*76 + r ; uint r = fp16 pair
// (U[k0+2r][col], U[k0+2r+1][col]), k0 = 152*(t/300), col = 300g+75*part+jj.
__global__ __launch_bounds__(256)
void kU_pack(const float* __restrict__ Uf, const float* __restrict__ Ub,
             unsigned* __restrict__ Upp)
{
    const int idx = blockIdx.x * 256 + threadIdx.x;   // < 364800
    const int r    = idx % UU;
    const int tB   = idx / UU;
    const int t    = tB % 600;
    const int dp   = tB / 600;
    const int part = dp & 3;
    const int dir  = dp >> 2;
    const int kh = t / 300, ci = t % 300;
    const int g  = ci / 75, jj = ci % 75;
    const int col = 300 * g + 75 * part + jj;
    const int k0  = 152 * kh + 2 * r;
    const float* __restrict__ U = dir ? Ub : Uf;
    float lo = (k0     < 300) ? U[(size_t)k0 * G4 + col]       : 0.f;
    float hi = (k0 + 1 < 300) ? U[(size_t)(k0 + 1) * G4 + col] : 0.f;
    __half2 h2 = __floats2half2_rn(lo, hi);
    Upp[idx] = *(unsigned*)&h2;
}

// ---------------- k_reset: zero step-flags (every launch; replay-safe) ------
__global__ __launch_bounds__(256)
void k_reset(unsigned* __restrict__ flags)
{
    flags[blockIdx.x * 256 + threadIdx.x] = 0u;
}

// ---------------- k_init: out[r][c] = bfc[c] --------------------------------
__global__ __launch_bounds__(256)
void k_init(float* __restrict__ out, const float* __restrict__ bfc)
{
    const size_t i = (size_t)blockIdx.x * 256 + threadIdx.x;
    out[i] = bfc[i & 63];
}

// ---------------- K2: persistent-register LSTM scan -------------------------
// 256 blocks (cooperative) = 64 pchains (32 batch-pairs x 2 dirs) x 4 parts.
// Part owns units [75*part, 75*part+75): all 4 gates, both batches.
// U slice lives in VGPRs (76 uints/thread x 600 dot threads = 180 KB fp16).
// Per step: gather partner h (flags+device-scope atomics) -> dots from regs
// -> gate merge -> nonlinearity -> publish h. FC projection fused (spare
// wave), atomicAdd into bfc-initialized out.
__global__ __launch_bounds__(NTH, 3)
void k2_rnn(const int* __restrict__ seqlen, const unsigned* __restrict__ Upp,
            const __half* __restrict__ xgf, const __half* __restrict__ xgb,
            const float* __restrict__ Wfc, float* __restrict__ out,
            float* __restrict__ hG, unsigned* __restrict__ flags)
{
    const int raw    = blockIdx.x;
    const int part   = (raw >> 3) & 3;                    // co-locate parts
    const int pchain = (raw & 7) | ((raw >> 5) << 3);     // on one XCD
    const int dir = pchain & 1;
    const int pr  = pchain >> 1;
    const int bA = 2 * pr, bB2 = 2 * pr + 1;
    const int LA = seqlen[bA], LB = seqlen[bB2];
    const int maxL = LA > LB ? LA : LB;
    const __half* __restrict__ xg = dir ? xgb : xgf;

    __shared__ __align__(16) float W2s[75][TAGS];    // 19.2 KB
    __shared__ __align__(16) float h32[2][304];      // padded, tail stays 0
    __shared__ __align__(16) float sfo[2][300];
    __shared__ __align__(16) float gtot[2][300];

    const int t = threadIdx.x;
    for (int i = t; i < 75 * TAGS; i += NTH)
        W2s[i >> 6][i & 63] = Wfc[(size_t)(dir * HID + 75 * part) * TAGS + i];
    for (int i = t; i < 2 * 304; i += NTH) ((float*)h32)[i] = 0.f;

    uint4 Ur[UQ];
    if (t < 600) {
        const uint4* ub = (const uint4*)Upp
                        + ((size_t)((dir * 4 + part) * 600 + t)) * UQ;
        #pragma unroll
        for (int q = 0; q < UQ; ++q) Ur[q] = ub[q];
    }
    __syncthreads();

    // dot identity (t<600)
    const int kh = t / 300, ci = t % 300;
    const int k0 = 152 * kh;
    const int gg = ci / 75, jj = ci % 75;
    const int mycol = 300 * gg + 75 * part + jj;
    // nonlin identity (t<150)
    const int nb = t / 75, nj = t % 75, nu = 75 * part + nj;
    const int myL = nb ? LB : LA;
    float cReg = 0.f;
    // gather identity (t<450): 3 partner parts x 2 batches x 75 units
    const int gp0 = t / 150;
    const int gpart = gp0 + (gp0 >= part);
    const int gj = t % 150, gb = gj / 75, gjj = gj % 75;
    // proj identity (t>=640)
    const int s = t - 640;

    unsigned* const fl_own = flags + (pchain * 4 + part) * 16;

    for (int ti = 0; ti < maxL; ++ti) {
        const int tf = dir ? (maxL - 1 - ti) : ti;

        if (ti > 0 && t < 450) {
            const unsigned* flp = flags + (pchain * 4 + gpart) * 16;
            while (__hip_atomic_load(flp, __ATOMIC_ACQUIRE,
                                     __HIP_MEMORY_SCOPE_AGENT) < (unsigned)ti)
                __builtin_amdgcn_s_sleep(2);
            unsigned v = __hip_atomic_load(
                (const unsigned*)hG + ((size_t)pchain * 2 + gb) * 304
                                    + 75 * gpart + gjj,
                __ATOMIC_RELAXED, __HIP_MEMORY_SCOPE_AGENT);
            h32[gb][75 * gpart + gjj] = __uint_as_float(v);
        }
        __syncthreads();                               // B1: h(ti-1) complete

        float accA = 0.f, accB = 0.f;
        if (t < 600) {
            if (kh == 0) {
                accA = __half2float(xg[((size_t)bA  * TT + tf) * G4 + mycol]);
                accB = __half2float(xg[((size_t)bB2 * TT + tf) * G4 + mycol]);
            }
            const float* hA_ = &h32[0][k0];
            const float* hB_ = &h32[1][k0];
            #pragma unroll
            for (int q = 0; q < UQ; ++q) {
                uint4 uq = Ur[q];
                f32x4 a0 = *(const f32x4*)&hA_[8 * q];
                f32x4 a1 = *(const f32x4*)&hA_[8 * q + 4];
                f32x4 b0 = *(const f32x4*)&hB_[8 * q];
                f32x4 b1 = *(const f32x4*)&hB_[8 * q + 4];
                float2 w;
                w = __half22float2(*(const __half2*)&uq.x);
                accA = fmaf(w.x, a0.x, accA); accA = fmaf(w.y, a0.y, accA);
                accB = fmaf(w.x, b0.x, accB); accB = fmaf(w.y, b0.y, accB);
                w = __half22float2(*(const __half2*)&uq.y);
                accA = fmaf(w.x, a0.z, accA); accA = fmaf(w.y, a0.w, accA);
                accB = fmaf(w.x, b0.z, accB); accB = fmaf(w.y, b0.w, accB);
                w = __half22float2(*(const __half2*)&uq.z);
                accA = fmaf(w.x, a1.x, accA); accA = fmaf(w.y, a1.y, accA);
                accB = fmaf(w.x, b1.x, accB); accB = fmaf(w.y, b1.y, accB);
                w = __half22float2(*(const __half2*)&uq.w);
                accA = fmaf(w.x, a1.z, accA); accA = fmaf(w.y, a1.w, accA);
                accB = fmaf(w.x, b1.z, accB); accB = fmaf(w.y, b1.w, accB);
            }
            if (kh) { sfo[0][ci] = accA; sfo[1][ci] = accB; }
        } else if (s >= 0 && ti > 0) {
            // FC projection of h(ti-1), overlapped with dots
            const int rowp = dir ? (tf + 1) : (tf - 1);
            float pA = 0.f, pB = 0.f;
            #pragma unroll 5
            for (int j = 0; j < 75; ++j) {
                float wv = W2s[j][s];
                pA = fmaf(h32[0][75 * part + j], wv, pA);
                pB = fmaf(h32[1][75 * part + j], wv, pB);
            }
            atomicAdd(out + ((size_t)bA  * TT + rowp) * TAGS + s, pA);
            atomicAdd(out + ((size_t)bB2 * TT + rowp) * TAGS + s, pB);
        }
        __syncthreads();                               // B2
        if (t < 300) {
            gtot[0][t] = accA + sfo[0][t];
            gtot[1][t] = accB + sfo[1][t];
        }
        __syncthreads();                               // B3
        if (t < 150) {
            float gi = gtot[nb][nj],       gf = gtot[nb][75 + nj];
            float gc = gtot[nb][150 + nj], go = gtot[nb][225 + nj];
            float i_ = sigm(gi), f_ = sigm(gf);
            float z  = tanh_fast(gc), o_ = sigm(go);
            float cn = fmaf(f_, cReg, i_ * z);
            float hn = o_ * tanh_fast(cn);
            if (tf < myL) cReg = cn; else hn = h32[nb][nu];   // freeze
            h32[nb][nu] = hn;
            __hip_atomic_store(
                (unsigned*)hG + ((size_t)pchain * 2 + nb) * 304 + nu,
                __float_as_uint(hn),
                __ATOMIC_RELAXED, __HIP_MEMORY_SCOPE_AGENT);
        }
        __syncthreads();                               // B4: publish complete
        if (t == 0) {
            __threadfence();
            __hip_atomic_store(fl_own, (unsigned)(ti + 1),
                               __ATOMIC_RELEASE, __HIP_MEMORY_SCOPE_AGENT);
        }
    }

    // final projection of h(maxL-1) + fwd tail fill
    if (s >= 0) {
        float pA = 0.f, pB = 0.f;
        for (int j = 0; j < 75; ++j) {
            float wv = W2s[j][s];
            pA = fmaf(h32[0][75 * part + j], wv, pA);
            pB = fmaf(h32[1][75 * part + j], wv, pB);
        }
        if (dir == 0) {
            for (int r = maxL - 1; r < TT; ++r) {
                atomicAdd(out + ((size_t)bA  * TT + r) * TAGS + s, pA);
                atomicAdd(out + ((size_t)bB2 * TT + r) * TAGS + s, pB);
            }
        } else {
            atomicAdd(out + ((size_t)bA  * TT) * TAGS + s, pA);
            atomicAdd(out + ((size_t)bB2 * TT) * TAGS + s, pB);
        }
    }
}

extern "C" void kernel_launch(void* const* d_in, const int* in_sizes, int n_in,
                              void* d_out, int out_size, void* d_ws, size_t ws_size,
                              hipStream_t stream)
{
    const int*   tokens = (const int*)d_in[0];
    const int*   seqlen = (const int*)d_in[1];
    const float* emb    = (const float*)d_in[2];
    const float* Wf     = (const float*)d_in[3];
    const float* Uf     = (const float*)d_in[4];
    const float* bf     = (const float*)d_in[5];
    const float* Wb     = (const float*)d_in[6];
    const float* Ub     = (const float*)d_in[7];
    const float* bb     = (const float*)d_in[8];
    const float* Wfc    = (const float*)d_in[9];
    const float* bfc    = (const float*)d_in[10];
    float* out = (float*)d_out;

    // ws: xgf fp16 | xgb fp16 | Upp (1.46MB) | hG (155KB) | flags (16KB)
    const size_t xg_elems  = (size_t)MM * G4;
    const size_t upp_uints = (size_t)2 * 4 * 600 * UU;       // 364800
    const size_t hg_floats = (size_t)64 * 2 * 304;
    const size_t fl_uints  = (size_t)64 * 4 * 16;
    const size_t need = xg_elems * 2 * sizeof(__half)
                      + upp_uints * 4 + hg_floats * 4 + fl_uints * 4;
    if (ws_size < need) {
        hipMemsetAsync(d_out, 0, (size_t)out_size * sizeof(float), stream);
        return;
    }
    __half*   xgf   = (__half*)d_ws;
    __half*   xgb   = xgf + xg_elems;
    unsigned* Upp   = (unsigned*)(xgb + xg_elems);
    float*    hG    = (float*)(Upp + upp_uints);
    unsigned* flags = (unsigned*)(hG + hg_floats);

    hipLaunchKernelGGL(k_reset, dim3(fl_uints / 256), dim3(256), 0, stream,
                       flags);
    hipLaunchKernelGGL(kU_pack, dim3(upp_uints / 256), dim3(256), 0, stream,
                       Uf, Ub, Upp);
    hipLaunchKernelGGL(k_init, dim3(MM * TAGS / 256), dim3(256), 0, stream,
                       out, bfc);
    dim3 g1(MM / 64, (G4 + 63) / 64, 2);
    hipLaunchKernelGGL(k1_xg, g1, dim3(256), 0, stream,
                       tokens, seqlen, emb, Wf, bf, Wb, bb, xgf, xgb);

    const int* seqlen_a = seqlen; const unsigned* Upp_a = Upp;
    const __half* xgf_a = xgf;   const __half* xgb_a = xgb;
    const float* Wfc_a = Wfc;    float* out_a = out;
    float* hG_a = hG;            unsigned* flags_a = flags;
    void* args[] = { (void*)&seqlen_a, (void*)&Upp_a, (void*)&xgf_a,
                     (void*)&xgb_a, (void*)&Wfc_a, (void*)&out_a,
                     (void*)&hG_a, (void*)&flags_a };
    hipLaunchCooperativeKernel((const void*)k2_rnn, dim3(NBLK), dim3(NTH),
                               args, 0, stream);
}

// Round 6
// 13546.916 us; speedup vs baseline: 1.9395x; 1.9395x over previous
//
#include <hip/hip_runtime.h>
#include <hip/hip_fp16.h>

typedef float f32x4 __attribute__((ext_vector_type(4)));
typedef _Float16 h2_t __attribute__((ext_vector_type(2)));

#define EMB   300
#define HID   300
#define G4    1200
#define TAGS  64
#define BB    64
#define TT    512
#define MM    (BB*TT)
#define KC_ALL 75
#define KC_LDS 58
#define KC_STR (KC_ALL - KC_LDS)   // 17
#define NTH   576
#define NBLK  256
// LDS: Us 58*300*8 | W2s 75*64*2 | h16 2*76*8 | gdot 2*304*4
#define SMEM_BYTES (KC_LDS*300*8 + 75*64*2 + 2*76*8 + 2*304*4)

__device__ __forceinline__ float sigm(float x) {
    return 1.0f / (1.0f + __expf(-x));
}
__device__ __forceinline__ float tanh_fast(float x) {
    float e = __expf(-2.0f * fabsf(x));
    float r = (1.0f - e) / (1.0f + e);
    return copysignf(r, x);
}
__device__ __forceinline__ float fdot2f(unsigned u, unsigned h, float acc) {
#if __has_builtin(__builtin_amdgcn_fdot2)
    return __builtin_amdgcn_fdot2(__builtin_bit_cast(h2_t, u),
                                  __builtin_bit_cast(h2_t, h), acc, false);
#else
    h2_t a = __builtin_bit_cast(h2_t, u), b = __builtin_bit_cast(h2_t, h);
    acc = fmaf((float)a.x, (float)b.x, acc);
    return fmaf((float)a.y, (float)b.y, acc);
#endif
}
__device__ __forceinline__ unsigned short f2h_bits(float f) {
    _Float16 h = (_Float16)f;
    return __builtin_bit_cast(unsigned short, h);
}
__device__ __forceinline__ float h_bits2f(unsigned short s) {
    return (float)__builtin_bit_cast(_Float16, s);
}

// ---------------- K1: xg = emb[tokens] @ W + bias, stored fp16 --------------
__global__ __launch_bounds__(256)
void k1_xg(const int* __restrict__ tokens, const int* __restrict__ seqlen,
           const float* __restrict__ emb,
           const float* __restrict__ Wf, const float* __restrict__ bf,
           const float* __restrict__ Wb, const float* __restrict__ bb,
           __half* __restrict__ xgf, __half* __restrict__ xgb)
{
    const int z = blockIdx.z;
    const float* __restrict__ W    = z ? Wb : Wf;
    const float* __restrict__ bias = z ? bb : bf;
    __half* __restrict__ out       = z ? xgb : xgf;

    const int row0 = blockIdx.x * 64;
    const int b    = row0 >> 9;
    const int t0   = row0 & 511;
    if (t0 >= seqlen[b]) return;       // whole strip masked -> never consumed

    const int n0 = blockIdx.y * 64;

    __shared__ __align__(16) float As[20][64];
    __shared__ __align__(16) float Bs[20][64];
    __shared__ int toks[64];

    const int tid = threadIdx.x;
    if (tid < 64) toks[tid] = tokens[row0 + tid];
    __syncthreads();

    const int tx = tid & 15, ty = tid >> 4;
    const int rm = ty * 4,   cn = tx * 4;

    float acc[4][4] = {{0.f}};

    const int ar  = tid & 63;
    const int ak0 = (tid >> 6) * 5;

    for (int kc = 0; kc < EMB; kc += 20) {
        const float* arow = emb + (size_t)toks[ar] * EMB + (kc + ak0);
        #pragma unroll
        for (int u = 0; u < 5; ++u) As[ak0 + u][ar] = arow[u];
        const int colb = n0 + ar;
        #pragma unroll
        for (int u = 0; u < 5; ++u) {
            float v = 0.f;
            if (colb < G4) v = W[(size_t)(kc + ak0 + u) * G4 + colb];
            Bs[ak0 + u][ar] = v;
        }
        __syncthreads();
        #pragma unroll
        for (int k = 0; k < 20; ++k) {
            f32x4 av = *(const f32x4*)&As[k][rm];
            f32x4 bv = *(const f32x4*)&Bs[k][cn];
            #pragma unroll
            for (int i = 0; i < 4; ++i)
                #pragma unroll
                for (int j = 0; j < 4; ++j)
                    acc[i][j] = fmaf(av[i], bv[j], acc[i][j]);
        }
        __syncthreads();
    }
    #pragma unroll
    for (int i = 0; i < 4; ++i) {
        const int row = row0 + rm + i;
        #pragma unroll
        for (int j = 0; j < 4; ++j) {
            const int col = n0 + cn + j;
            if (col < G4)
                out[(size_t)row * G4 + col] = __float2half(acc[i][j] + bias[col]);
        }
    }
}

// ---------------- kU: pack U -> fp16, [dir][part][kc][ci] uint2 -------------
// entry = halves (U[4kc+0][col],U[4kc+1][col] | U[4kc+2][col],U[4kc+3][col]),
// col = 300*(ci/75) + 75*part + ci%75.
__global__ __launch_bounds__(256)
void kU_pack(const float* __restrict__ Uf, const float* __restrict__ Ub,
             uint2* __restrict__ Upk2)
{
    const int idx = blockIdx.x * 256 + threadIdx.x;
    if (idx >= 2 * 4 * KC_ALL * 300) return;
    const int dp  = idx / (KC_ALL * 300);
    const int rem = idx % (KC_ALL * 300);
    const int kc  = rem / 300;
    const int ci  = rem % 300;
    const int part = dp & 3, dir = dp >> 2;
    const int col = 300 * (ci / 75) + 75 * part + (ci % 75);
    const int k0  = 4 * kc;
    const float* __restrict__ U = dir ? Ub : Uf;
    __half2 lo = __floats2half2_rn(U[(size_t)(k0 + 0) * G4 + col],
                                   U[(size_t)(k0 + 1) * G4 + col]);
    __half2 hi = __floats2half2_rn(U[(size_t)(k0 + 2) * G4 + col],
                                   U[(size_t)(k0 + 3) * G4 + col]);
    uint2 v;
    v.x = *(unsigned*)&lo;
    v.y = *(unsigned*)&hi;
    Upk2[idx] = v;
}

// ---------------- k_reset / k_init ------------------------------------------
__global__ __launch_bounds__(256)
void k_reset(unsigned* __restrict__ flags)
{
    flags[blockIdx.x * 256 + threadIdx.x] = 0u;
}
__global__ __launch_bounds__(256)
void k_init(float* __restrict__ out, const float* __restrict__ bfc)
{
    const size_t i = (size_t)blockIdx.x * 256 + threadIdx.x;
    out[i] = bfc[i & 63];
}

// ---------------- K2: LDS-resident-U LSTM scan (cooperative) ----------------
// 256 blocks = 64 pchains x 4 parts, 576 threads, ~152 KB dynamic LDS.
// Part owns units [75p,75p+75): all 4 gates, both batches. U slice: 58/75
// k-chunks in LDS, 17 streamed from L2 each step. Dots via v_dot2_f32_f16
// (h fp16 in LDS). Per-step cross-part h exchange via hG + flags (R5
// protocol). FC projection fused on a spare wave, atomicAdd into out.
__global__ __launch_bounds__(NTH)
void k2_rnn(const int* __restrict__ seqlen, const uint2* __restrict__ Upk2,
            const __half* __restrict__ xgf, const __half* __restrict__ xgb,
            const float* __restrict__ Wfc, float* __restrict__ out,
            float* __restrict__ hG, unsigned* __restrict__ flags)
{
    const int raw    = blockIdx.x;
    const int part   = (raw >> 3) & 3;                 // parts of a pchain
    const int pchain = (raw & 7) | ((raw >> 5) << 3);  // share an XCD slot
    const int dir = pchain & 1;
    const int pr  = pchain >> 1;
    const int bA = 2 * pr, bB2 = 2 * pr + 1;
    const int LA = seqlen[bA], LB = seqlen[bB2];
    const int maxL = LA > LB ? LA : LB;
    const int dp = dir * 4 + part;
    const __half* __restrict__ xg = dir ? xgb : xgf;

    extern __shared__ __align__(16) char smem[];
    uint2*          Us   = (uint2*)smem;                      // [58*300]
    unsigned short* W2s  = (unsigned short*)(Us + KC_LDS*300);// [75*64]
    uint2*          h16  = (uint2*)(W2s + 75 * 64);           // [2*76]
    float*          gdot = (float*)(h16 + 2 * 76);            // [2*304]
    unsigned short* h16s = (unsigned short*)h16;

    const int t = threadIdx.x;

    // one-time staging
    const uint2* Ug = Upk2 + (size_t)dp * KC_ALL * 300;
    for (int i = t; i < KC_LDS * 300; i += NTH) Us[i] = Ug[i];
    for (int i = t; i < 75 * 64; i += NTH) {
        const int j = i >> 6, s2 = i & 63;
        W2s[i] = f2h_bits(Wfc[(size_t)(dir * HID + 75 * part + j) * TAGS + s2]);
    }
    for (int i = t; i < 2 * 304; i += NTH) h16s[i] = 0;
    __syncthreads();

    // identities
    const int g = (t < 300) ? t / 75 : 0, jj5 = (t < 300) ? t % 75 : 0;
    const int mycol = 300 * g + 75 * part + jj5;               // dot col
    const int nb = (t < 150) ? t / 75 : 0, nj = t % 75;        // nonlin
    const int nu = 75 * part + nj;
    const int myL = nb ? LB : LA;
    float cReg = 0.f;
    const int gp0 = t / 150;                                   // gather
    const int gpart = gp0 + (gp0 >= part);
    const int gj = t % 150, gb = gj / 75, gjj = gj % 75;
    const int s = t - 512;                                     // proj col

    unsigned* const fl_own = flags + (pchain * 4 + part) * 16;

    for (int ti = 0; ti < maxL; ++ti) {
        const int tf = dir ? (maxL - 1 - ti) : ti;

        // ---- phase A: gather partner h(ti-1) ----
        if (ti > 0 && t < 450) {
            const unsigned* flp = flags + (pchain * 4 + gpart) * 16;
            while (__hip_atomic_load(flp, __ATOMIC_ACQUIRE,
                                     __HIP_MEMORY_SCOPE_AGENT) < (unsigned)ti)
                __builtin_amdgcn_s_sleep(2);
            unsigned v = __hip_atomic_load(
                (const unsigned*)hG + ((size_t)pchain * 2 + gb) * 304
                                    + 75 * gpart + gjj,
                __ATOMIC_RELAXED, __HIP_MEMORY_SCOPE_AGENT);
            h16s[gb * 304 + 75 * gpart + gjj] =
                f2h_bits(__uint_as_float(v));
        }
        __syncthreads();                                   // B1

        // ---- phase B: dots (t<300) | FC proj (t>=512) ----
        if (t < 300) {
            float accA = __half2float(xg[((size_t)bA  * TT + tf) * G4 + mycol]);
            float accB = __half2float(xg[((size_t)bB2 * TT + tf) * G4 + mycol]);
            // streamed k-chunks: issue loads first
            uint2 ustr[KC_STR];
            const uint2* gsrc = Ug + (size_t)KC_LDS * 300 + t;
            #pragma unroll
            for (int q = 0; q < KC_STR; ++q) ustr[q] = gsrc[q * 300];
            const uint2* hA2 = h16;
            const uint2* hB2 = h16 + 76;
            #pragma unroll
            for (int kc = 0; kc < KC_LDS; ++kc) {
                uint2 u  = Us[kc * 300 + t];
                uint2 ha = hA2[kc], hb = hB2[kc];
                accA = fdot2f(u.x, ha.x, accA);
                accA = fdot2f(u.y, ha.y, accA);
                accB = fdot2f(u.x, hb.x, accB);
                accB = fdot2f(u.y, hb.y, accB);
            }
            #pragma unroll
            for (int q = 0; q < KC_STR; ++q) {
                uint2 u  = ustr[q];
                uint2 ha = hA2[KC_LDS + q], hb = hB2[KC_LDS + q];
                accA = fdot2f(u.x, ha.x, accA);
                accA = fdot2f(u.y, ha.y, accA);
                accB = fdot2f(u.x, hb.x, accB);
                accB = fdot2f(u.y, hb.y, accB);
            }
            gdot[t] = accA;
            gdot[304 + t] = accB;
        } else if (s >= 0 && ti > 0) {
            const int rowp = dir ? (tf + 1) : (tf - 1);
            float pA = 0.f, pB = 0.f;
            #pragma unroll 5
            for (int j = 0; j < 75; ++j) {
                float wv = h_bits2f(W2s[j * 64 + s]);
                pA = fmaf(h_bits2f(h16s[75 * part + j]), wv, pA);
                pB = fmaf(h_bits2f(h16s[304 + 75 * part + j]), wv, pB);
            }
            atomicAdd(out + ((size_t)bA  * TT + rowp) * TAGS + s, pA);
            atomicAdd(out + ((size_t)bB2 * TT + rowp) * TAGS + s, pB);
        }
        __syncthreads();                                   // B2

        // ---- phase C: nonlinearity + publish ----
        if (t < 150) {
            float gi = gdot[nb * 304 + nj];
            float gf = gdot[nb * 304 + 75 + nj];
            float gc = gdot[nb * 304 + 150 + nj];
            float go = gdot[nb * 304 + 225 + nj];
            float i_ = sigm(gi), f_ = sigm(gf);
            float z  = tanh_fast(gc), o_ = sigm(go);
            float cn = fmaf(f_, cReg, i_ * z);
            float hn = o_ * tanh_fast(cn);
            if (tf < myL) cReg = cn;
            else          hn = h_bits2f(h16s[nb * 304 + nu]);   // freeze
            h16s[nb * 304 + nu] = f2h_bits(hn);
            __hip_atomic_store(
                (unsigned*)hG + ((size_t)pchain * 2 + nb) * 304 + nu,
                __float_as_uint(hn),
                __ATOMIC_RELAXED, __HIP_MEMORY_SCOPE_AGENT);
        }
        __syncthreads();                                   // B3
        if (t == 0) {
            __threadfence();
            __hip_atomic_store(fl_own, (unsigned)(ti + 1),
                               __ATOMIC_RELEASE, __HIP_MEMORY_SCOPE_AGENT);
        }
    }

    // final projection of h(maxL-1) + tail fill
    if (s >= 0) {
        float pA = 0.f, pB = 0.f;
        for (int j = 0; j < 75; ++j) {
            float wv = h_bits2f(W2s[j * 64 + s]);
            pA = fmaf(h_bits2f(h16s[75 * part + j]), wv, pA);
            pB = fmaf(h_bits2f(h16s[304 + 75 * part + j]), wv, pB);
        }
        if (dir == 0) {
            for (int r = maxL - 1; r < TT; ++r) {
                atomicAdd(out + ((size_t)bA  * TT + r) * TAGS + s, pA);
                atomicAdd(out + ((size_t)bB2 * TT + r) * TAGS + s, pB);
            }
        } else {
            atomicAdd(out + ((size_t)bA  * TT) * TAGS + s, pA);
            atomicAdd(out + ((size_t)bB2 * TT) * TAGS + s, pB);
        }
    }
}

extern "C" void kernel_launch(void* const* d_in, const int* in_sizes, int n_in,
                              void* d_out, int out_size, void* d_ws, size_t ws_size,
                              hipStream_t stream)
{
    const int*   tokens = (const int*)d_in[0];
    const int*   seqlen = (const int*)d_in[1];
    const float* emb    = (const float*)d_in[2];
    const float* Wf     = (const float*)d_in[3];
    const float* Uf     = (const float*)d_in[4];
    const float* bf     = (const float*)d_in[5];
    const float* Wb     = (const float*)d_in[6];
    const float* Ub     = (const float*)d_in[7];
    const float* bb     = (const float*)d_in[8];
    const float* Wfc    = (const float*)d_in[9];
    const float* bfc    = (const float*)d_in[10];
    float* out = (float*)d_out;

    // ws: xgf fp16 | xgb fp16 | Upk2 (1.44MB) | hG (156KB) | flags (16KB)
    const size_t xg_elems  = (size_t)MM * G4;
    const size_t up_elems  = (size_t)2 * 4 * KC_ALL * 300;   // uint2 entries
    const size_t hg_floats = (size_t)64 * 2 * 304;
    const size_t fl_uints  = (size_t)64 * 4 * 16;
    const size_t need = xg_elems * 2 * sizeof(__half)
                      + up_elems * sizeof(uint2)
                      + hg_floats * 4 + fl_uints * 4;
    if (ws_size < need) {
        hipMemsetAsync(d_out, 0, (size_t)out_size * sizeof(float), stream);
        return;
    }
    __half*   xgf   = (__half*)d_ws;
    __half*   xgb   = xgf + xg_elems;
    uint2*    Upk2  = (uint2*)(xgb + xg_elems);
    float*    hG    = (float*)(Upk2 + up_elems);
    unsigned* flags = (unsigned*)(hG + hg_floats);

    hipLaunchKernelGGL(k_reset, dim3(fl_uints / 256), dim3(256), 0, stream,
                       flags);
    hipLaunchKernelGGL(kU_pack, dim3((2 * 4 * KC_ALL * 300 + 255) / 256),
                       dim3(256), 0, stream, Uf, Ub, Upk2);
    hipLaunchKernelGGL(k_init, dim3(MM * TAGS / 256), dim3(256), 0, stream,
                       out, bfc);
    dim3 g1(MM / 64, (G4 + 63) / 64, 2);
    hipLaunchKernelGGL(k1_xg, g1, dim3(256), 0, stream,
                       tokens, seqlen, emb, Wf, bf, Wb, bb, xgf, xgb);

    hipFuncSetAttribute((const void*)k2_rnn,
                        hipFuncAttributeMaxDynamicSharedMemorySize,
                        SMEM_BYTES);
    const int* seqlen_a = seqlen; const uint2* Upk2_a = Upk2;
    const __half* xgf_a = xgf;   const __half* xgb_a = xgb;
    const float* Wfc_a = Wfc;    float* out_a = out;
    float* hG_a = hG;            unsigned* flags_a = flags;
    void* args[] = { (void*)&seqlen_a, (void*)&Upk2_a, (void*)&xgf_a,
                     (void*)&xgb_a, (void*)&Wfc_a, (void*)&out_a,
                     (void*)&hG_a, (void*)&flags_a };
    hipLaunchCooperativeKernel((const void*)k2_rnn, dim3(NBLK), dim3(NTH),
                               args, SMEM_BYTES, stream);
}

// Round 7
// 3863.379 us; speedup vs baseline: 6.8009x; 3.5065x over previous
//
#include <hip/hip_runtime.h>
#include <hip/hip_fp16.h>

typedef float f32x4 __attribute__((ext_vector_type(4)));
typedef _Float16 h2_t __attribute__((ext_vector_type(2)));

#define EMB   300
#define HID   300
#define G4    1200
#define TAGS  64
#define BB    64
#define TT    512
#define MM    (BB*TT)
#define KQ    38             // uint4 (8 fp16) k-chunks: 304 k, 300 real + 4 pad
#define NTH   704

__device__ __forceinline__ float sigm(float x) {
    return 1.0f / (1.0f + __expf(-x));
}
__device__ __forceinline__ float tanh_fast(float x) {
    float e = __expf(-2.0f * fabsf(x));
    float r = (1.0f - e) / (1.0f + e);
    return copysignf(r, x);
}
__device__ __forceinline__ float fdot2f(unsigned u, unsigned h, float acc) {
#if __has_builtin(__builtin_amdgcn_fdot2)
    return __builtin_amdgcn_fdot2(__builtin_bit_cast(h2_t, u),
                                  __builtin_bit_cast(h2_t, h), acc, false);
#else
    h2_t a = __builtin_bit_cast(h2_t, u), b = __builtin_bit_cast(h2_t, h);
    acc = fmaf((float)a.x, (float)b.x, acc);
    return fmaf((float)a.y, (float)b.y, acc);
#endif
}
__device__ __forceinline__ unsigned short f2h_bits(float f) {
    _Float16 h = (_Float16)f;
    return __builtin_bit_cast(unsigned short, h);
}

// ---------------- K1: xg = emb[tokens] @ W + bias, stored fp16 --------------
__global__ __launch_bounds__(256)
void k1_xg(const int* __restrict__ tokens, const int* __restrict__ seqlen,
           const float* __restrict__ emb,
           const float* __restrict__ Wf, const float* __restrict__ bf,
           const float* __restrict__ Wb, const float* __restrict__ bb,
           __half* __restrict__ xgf, __half* __restrict__ xgb)
{
    const int z = blockIdx.z;
    const float* __restrict__ W    = z ? Wb : Wf;
    const float* __restrict__ bias = z ? bb : bf;
    __half* __restrict__ out       = z ? xgb : xgf;

    const int row0 = blockIdx.x * 64;
    const int b    = row0 >> 9;
    const int t0   = row0 & 511;
    if (t0 >= seqlen[b]) return;       // whole strip masked -> never consumed

    const int n0 = blockIdx.y * 64;

    __shared__ __align__(16) float As[20][64];
    __shared__ __align__(16) float Bs[20][64];
    __shared__ int toks[64];

    const int tid = threadIdx.x;
    if (tid < 64) toks[tid] = tokens[row0 + tid];
    __syncthreads();

    const int tx = tid & 15, ty = tid >> 4;
    const int rm = ty * 4,   cn = tx * 4;

    float acc[4][4] = {{0.f}};

    const int ar  = tid & 63;
    const int ak0 = (tid >> 6) * 5;

    for (int kc = 0; kc < EMB; kc += 20) {
        const float* arow = emb + (size_t)toks[ar] * EMB + (kc + ak0);
        #pragma unroll
        for (int u = 0; u < 5; ++u) As[ak0 + u][ar] = arow[u];
        const int colb = n0 + ar;
        #pragma unroll
        for (int u = 0; u < 5; ++u) {
            float v = 0.f;
            if (colb < G4) v = W[(size_t)(kc + ak0 + u) * G4 + colb];
            Bs[ak0 + u][ar] = v;
        }
        __syncthreads();
        #pragma unroll
        for (int k = 0; k < 20; ++k) {
            f32x4 av = *(const f32x4*)&As[k][rm];
            f32x4 bv = *(const f32x4*)&Bs[k][cn];
            #pragma unroll
            for (int i = 0; i < 4; ++i)
                #pragma unroll
                for (int j = 0; j < 4; ++j)
                    acc[i][j] = fmaf(av[i], bv[j], acc[i][j]);
        }
        __syncthreads();
    }
    #pragma unroll
    for (int i = 0; i < 4; ++i) {
        const int row = row0 + rm + i;
        #pragma unroll
        for (int j = 0; j < 4; ++j) {
            const int col = n0 + cn + j;
            if (col < G4)
                out[(size_t)row * G4 + col] = __float2half(acc[i][j] + bias[col]);
        }
    }
}

// ---------------- kU: pack U -> fp16 [dir][kq][col] uint4 -------------------
// entry (kq,col) = halves of U[8kq+0 .. 8kq+7][col], zero-padded past k=299.
__global__ __launch_bounds__(256)
void kU_pack(const float* __restrict__ Uf, const float* __restrict__ Ub,
             uint4* __restrict__ Upk4f, uint4* __restrict__ Upk4b)
{
    const int idx = blockIdx.x * 256 + threadIdx.x;
    if (idx >= 2 * KQ * G4) return;
    const int dir = idx / (KQ * G4);
    const int rem = idx % (KQ * G4);
    const int kq  = rem / G4;
    const int col = rem % G4;
    const float* __restrict__ U = dir ? Ub : Uf;
    float v[8];
    #pragma unroll
    for (int u = 0; u < 8; ++u) {
        const int k = 8 * kq + u;
        v[u] = (k < HID) ? U[(size_t)k * G4 + col] : 0.f;
    }
    __half2 p0 = __floats2half2_rn(v[0], v[1]);
    __half2 p1 = __floats2half2_rn(v[2], v[3]);
    __half2 p2 = __floats2half2_rn(v[4], v[5]);
    __half2 p3 = __floats2half2_rn(v[6], v[7]);
    uint4 o;
    o.x = *(unsigned*)&p0; o.y = *(unsigned*)&p1;
    o.z = *(unsigned*)&p2; o.w = *(unsigned*)&p3;
    (dir ? Upk4b : Upk4f)[rem] = o;
}

// ---------------- k_init: out[r][c] = bfc[c] --------------------------------
__global__ __launch_bounds__(256)
void k_init(float* __restrict__ out, const float* __restrict__ bfc)
{
    const size_t i = (size_t)blockIdx.x * 256 + threadIdx.x;
    out[i] = bfc[i & 63];
}

// ---------------- K2: LSTM scan, wide-load U stream, fused FC ---------------
// 128 blocks = 64 batches x 2 dirs, 704 threads, ~83 KB LDS.
//   tid 0..599   : dot threads. Thread t owns gate-cols t and t+600; full
//                  300-k dot via 38 coalesced uint4 loads per col (16B = 8
//                  fp16). Dots with v_dot2_f32_f16 against fp16 h (LDS,
//                  double-buffered). Threads >=300 hand (f,o) to partner
//                  via sfo; threads <300 run the nonlinearity, keep c in
//                  a register, write h both f32 (proj) and fp16 (dots).
//   tid 640..703 : project previous step's h (f32) through Wfc half (LDS),
//                  atomicAdd into bfc-initialized out; overlapped with dots.
// Exactly L steps per chain; 2 barriers/step.
__global__ __launch_bounds__(NTH)
void k2_rnn(const int* __restrict__ seqlen,
            const uint4* __restrict__ Upk4f, const uint4* __restrict__ Upk4b,
            const __half* __restrict__ xgf, const __half* __restrict__ xgb,
            const float* __restrict__ Wfc, float* __restrict__ out)
{
    const int w   = blockIdx.x;
    const int dir = w & 1;
    const int b   = w >> 1;
    const int L   = seqlen[b];
    const uint4* __restrict__ Up  = dir ? Upk4b : Upk4f;
    const __half* __restrict__ xg = dir ? xgb  : xgf;

    __shared__ __align__(16) float          W2s[HID][TAGS];  // 76.8 KB
    __shared__ __align__(16) float          h32[2][304];
    __shared__ __align__(16) unsigned short h16[2][304];
    __shared__ __align__(16) float2         sfo[300];

    const int t = threadIdx.x;
    for (int i = t; i < HID * TAGS; i += NTH)
        W2s[i >> 6][i & 63] = Wfc[(size_t)dir * HID * TAGS + i];
    for (int i = t; i < 2 * 304; i += NTH) {
        ((float*)h32)[i] = 0.f;
        ((unsigned short*)h16)[i] = 0;
    }
    __syncthreads();

    float c = 0.f;
    const int pcol = t - 640;     // proj col if >= 0

    for (int ti = 0; ti < L; ++ti) {
        const int tf = dir ? (L - 1 - ti) : ti;
        const int rb = ti & 1;

        float d0 = 0.f, d1 = 0.f;
        if (t < 600) {
            const size_t xbase = ((size_t)b * TT + tf) * G4;
            d0 = __half2float(xg[xbase + t]);
            d1 = __half2float(xg[xbase + t + 600]);
            const uint4* u0p = Up + t;
            const uint4* u1p = Up + t + 600;
            const uint4* hq  = (const uint4*)h16[rb];
            #pragma unroll 8
            for (int kq = 0; kq < KQ; ++kq) {
                uint4 u0 = u0p[(size_t)kq * G4];
                uint4 u1 = u1p[(size_t)kq * G4];
                uint4 hh = hq[kq];
                d0 = fdot2f(u0.x, hh.x, d0);
                d0 = fdot2f(u0.y, hh.y, d0);
                d0 = fdot2f(u0.z, hh.z, d0);
                d0 = fdot2f(u0.w, hh.w, d0);
                d1 = fdot2f(u1.x, hh.x, d1);
                d1 = fdot2f(u1.y, hh.y, d1);
                d1 = fdot2f(u1.z, hh.z, d1);
                d1 = fdot2f(u1.w, hh.w, d1);
            }
            if (t >= 300) sfo[t - 300] = make_float2(d0, d1);
        } else if (pcol >= 0 && ti > 0) {
            // project h of previous step (buffer rb), overlapped with dots
            const float* hs = h32[rb];
            float acc = 0.f;
            for (int j2 = 0; j2 < HID; j2 += 4) {
                f32x4 h4 = *(const f32x4*)&hs[j2];
                acc = fmaf(h4.x, W2s[j2 + 0][pcol], acc);
                acc = fmaf(h4.y, W2s[j2 + 1][pcol], acc);
                acc = fmaf(h4.z, W2s[j2 + 2][pcol], acc);
                acc = fmaf(h4.w, W2s[j2 + 3][pcol], acc);
            }
            const int rowp = dir ? (tf + 1) : (tf - 1);
            atomicAdd(out + ((size_t)b * TT + rowp) * TAGS + pcol, acc);
        }
        __syncthreads();
        if (t < 300) {
            float2 fo = sfo[t];
            float i_ = sigm(d0);
            float z  = tanh_fast(d1);
            float f_ = sigm(fo.x);
            float o_ = sigm(fo.y);
            c = fmaf(f_, c, i_ * z);
            float hn = o_ * tanh_fast(c);
            h32[rb ^ 1][t] = hn;
            h16[rb ^ 1][t] = f2h_bits(hn);
        }
        __syncthreads();
    }

    // final projection (h of step L-1 is in buffer L&1) + tail fill
    if (pcol >= 0) {
        const float* hs = h32[L & 1];
        float acc = 0.f;
        for (int j2 = 0; j2 < HID; j2 += 4) {
            f32x4 h4 = *(const f32x4*)&hs[j2];
            acc = fmaf(h4.x, W2s[j2 + 0][pcol], acc);
            acc = fmaf(h4.y, W2s[j2 + 1][pcol], acc);
            acc = fmaf(h4.z, W2s[j2 + 2][pcol], acc);
            acc = fmaf(h4.w, W2s[j2 + 3][pcol], acc);
        }
        if (dir == 0) {
            // fwd: rows [L-1, 512) all carry the final h projection
            float* o = out + (size_t)b * TT * TAGS + pcol;
            for (int tt = L - 1; tt < TT; ++tt)
                atomicAdd(o + (size_t)tt * TAGS, acc);
        } else {
            // bwd: final scan step is t=0; rows >= L contribute exactly 0
            atomicAdd(out + (size_t)b * TT * TAGS + pcol, acc);
        }
    }
}

extern "C" void kernel_launch(void* const* d_in, const int* in_sizes, int n_in,
                              void* d_out, int out_size, void* d_ws, size_t ws_size,
                              hipStream_t stream)
{
    const int*   tokens = (const int*)d_in[0];
    const int*   seqlen = (const int*)d_in[1];
    const float* emb    = (const float*)d_in[2];
    const float* Wf     = (const float*)d_in[3];
    const float* Uf     = (const float*)d_in[4];
    const float* bf     = (const float*)d_in[5];
    const float* Wb     = (const float*)d_in[6];
    const float* Ub     = (const float*)d_in[7];
    const float* bb     = (const float*)d_in[8];
    const float* Wfc    = (const float*)d_in[9];
    const float* bfc    = (const float*)d_in[10];
    float* out = (float*)d_out;

    // ws layout: xgf fp16 | xgb fp16 | Upk4f | Upk4b (729.6 KB each)
    const size_t xg_elems = (size_t)MM * G4;
    const size_t up_elems = (size_t)KQ * G4;     // uint4 entries per dir
    const size_t need = xg_elems * 2 * sizeof(__half)
                      + 2 * up_elems * sizeof(uint4);
    if (ws_size < need) {
        hipMemsetAsync(d_out, 0, (size_t)out_size * sizeof(float), stream);
        return;
    }
    __half* xgf   = (__half*)d_ws;
    __half* xgb   = xgf + xg_elems;
    uint4*  Upk4f = (uint4*)(xgb + xg_elems);
    uint4*  Upk4b = Upk4f + up_elems;

    hipLaunchKernelGGL(kU_pack, dim3((2 * KQ * G4 + 255) / 256), dim3(256),
                       0, stream, Uf, Ub, Upk4f, Upk4b);
    hipLaunchKernelGGL(k_init, dim3(MM * TAGS / 256), dim3(256), 0, stream,
                       out, bfc);
    dim3 g1(MM / 64, (G4 + 63) / 64, 2);
    hipLaunchKernelGGL(k1_xg, g1, dim3(256), 0, stream,
                       tokens, seqlen, emb, Wf, bf, Wb, bb, xgf, xgb);
    hipLaunchKernelGGL(k2_rnn, dim3(2 * BB), dim3(NTH), 0, stream,
                       seqlen, Upk4f, Upk4b, xgf, xgb, Wfc, out);
}

// Round 8
// 3360.361 us; speedup vs baseline: 7.8190x; 1.1497x over previous
//
#include <hip/hip_runtime.h>
#include <hip/hip_fp16.h>

typedef float f32x4 __attribute__((ext_vector_type(4)));
typedef _Float16 half8 __attribute__((ext_vector_type(8)));
typedef _Float16 h2_t __attribute__((ext_vector_type(2)));

#define EMB   300
#define HID   300
#define G4    1200
#define TAGS  64
#define BB    64
#define TT    512
#define MM    (BB*TT)
#define KQ    38        // uint4 (8 fp16) k-chunks: 304 k (300 + 4 pad)
#define NC    5         // k-chunks of U cached in LDS
#define NTH   704
#define WCOLS 1216      // padded col count of Wht
#define WK    320       // padded k of Wht
// k2 dynamic LDS: Us | W2s | h32 | h16 | sfo
#define SMEM2 (NC*1200*16 + 300*64*2 + 2*304*4 + 2*304*2 + 300*8)

__device__ __forceinline__ float sigm(float x) {
    return 1.0f / (1.0f + __expf(-x));
}
__device__ __forceinline__ float tanh_fast(float x) {
    float e = __expf(-2.0f * fabsf(x));
    float r = (1.0f - e) / (1.0f + e);
    return copysignf(r, x);
}
__device__ __forceinline__ float fdot2f(unsigned u, unsigned h, float acc) {
#if __has_builtin(__builtin_amdgcn_fdot2)
    return __builtin_amdgcn_fdot2(__builtin_bit_cast(h2_t, u),
                                  __builtin_bit_cast(h2_t, h), acc, false);
#else
    h2_t a = __builtin_bit_cast(h2_t, u), b = __builtin_bit_cast(h2_t, h);
    acc = fmaf((float)a.x, (float)b.x, acc);
    return fmaf((float)a.y, (float)b.y, acc);
#endif
}
__device__ __forceinline__ unsigned short f2h_bits(float f) {
    _Float16 h = (_Float16)f;
    return __builtin_bit_cast(unsigned short, h);
}
__device__ __forceinline__ float h_bits2f(unsigned short s) {
    return (float)__builtin_bit_cast(_Float16, s);
}

// ---------------- kW: W -> fp16, transposed + padded: Wht[dir][col][k] ------
__global__ __launch_bounds__(256)
void kW_pack(const float* __restrict__ Wf, const float* __restrict__ Wb,
             _Float16* __restrict__ Wht)
{
    const int idx = blockIdx.x * 256 + threadIdx.x;   // < 2*1216*320
    const int dir = idx / (WCOLS * WK);
    const int rem = idx % (WCOLS * WK);
    const int col = rem / WK;
    const int k   = rem % WK;
    const float* __restrict__ W = dir ? Wb : Wf;
    float v = (col < G4 && k < HID) ? W[(size_t)k * G4 + col] : 0.f;
    Wht[idx] = (_Float16)v;
}

// ---------------- kU: pack U -> fp16 [dir][kq][col] uint4 -------------------
__global__ __launch_bounds__(256)
void kU_pack(const float* __restrict__ Uf, const float* __restrict__ Ub,
             uint4* __restrict__ Upk4f, uint4* __restrict__ Upk4b)
{
    const int idx = blockIdx.x * 256 + threadIdx.x;
    if (idx >= 2 * KQ * G4) return;
    const int dir = idx / (KQ * G4);
    const int rem = idx % (KQ * G4);
    const int kq  = rem / G4;
    const int col = rem % G4;
    const float* __restrict__ U = dir ? Ub : Uf;
    float v[8];
    #pragma unroll
    for (int u = 0; u < 8; ++u) {
        const int k = 8 * kq + u;
        v[u] = (k < HID) ? U[(size_t)k * G4 + col] : 0.f;
    }
    __half2 p0 = __floats2half2_rn(v[0], v[1]);
    __half2 p1 = __floats2half2_rn(v[2], v[3]);
    __half2 p2 = __floats2half2_rn(v[4], v[5]);
    __half2 p3 = __floats2half2_rn(v[6], v[7]);
    uint4 o;
    o.x = *(unsigned*)&p0; o.y = *(unsigned*)&p1;
    o.z = *(unsigned*)&p2; o.w = *(unsigned*)&p3;
    (dir ? Upk4b : Upk4f)[rem] = o;
}

// ---------------- k_init: out[r][c] = bfc[c] --------------------------------
__global__ __launch_bounds__(256)
void k_init(float* __restrict__ out, const float* __restrict__ bfc)
{
    const size_t i = (size_t)blockIdx.x * 256 + threadIdx.x;
    out[i] = bfc[i & 63];
}

// ---------------- K1: xg = emb[tokens] @ W + bias via MFMA fp16 -------------
// grid (512, 19, 2), 256 thr = 4 waves. 64x64 tile, k-loop 10x32 (padded 320).
// Output packed: xgp[row][ (col%600)*2 + (col>=600) ].
__global__ __launch_bounds__(256)
void k1_xg(const int* __restrict__ tokens, const int* __restrict__ seqlen,
           const float* __restrict__ emb, const _Float16* __restrict__ Wht,
           const float* __restrict__ bf, const float* __restrict__ bb,
           __half* __restrict__ xgpf, __half* __restrict__ xgpb)
{
    const int z = blockIdx.z;
    const _Float16* __restrict__ Wh = Wht + (size_t)z * WCOLS * WK;
    const float* __restrict__ bias  = z ? bb : bf;
    __half* __restrict__ xgp        = z ? xgpb : xgpf;

    const int row0 = blockIdx.x * 64;
    const int b    = row0 >> 9;
    const int t0   = row0 & 511;
    if (t0 >= seqlen[b]) return;       // strip fully masked -> never consumed

    const int n0 = blockIdx.y * 64;

    __shared__ int toks[64];
    __shared__ __align__(16) _Float16 A_lds[64][40];
    __shared__ __align__(16) _Float16 B_lds[64][40];

    const int tid = threadIdx.x;
    if (tid < 64) toks[tid] = tokens[row0 + tid];
    __syncthreads();

    const int r = tid >> 2, q = tid & 3;     // staging identity
    const int lane = tid & 63, w = tid >> 6;
    const int lr = lane & 15, lk = lane >> 4;

    f32x4 acc[4];
    #pragma unroll
    for (int ct = 0; ct < 4; ++ct) acc[ct] = (f32x4){0.f, 0.f, 0.f, 0.f};

    const float* er = emb + (size_t)toks[r] * EMB;

    for (int kc = 0; kc < WK; kc += 32) {
        // A stage: row r, k = kc + q*8 .. +8 (guarded, from f32 emb)
        {
            half8 av;
            #pragma unroll
            for (int u = 0; u < 8; ++u) {
                const int k = kc + q * 8 + u;
                av[u] = (k < EMB) ? (_Float16)er[k] : (_Float16)0.f;
            }
            *(half8*)&A_lds[r][q * 8] = av;
        }
        // B stage: col n0+r, k contiguous from pre-transposed fp16 Wht
        *(half8*)&B_lds[r][q * 8] =
            *(const half8*)(Wh + (size_t)(n0 + r) * WK + kc + q * 8);
        __syncthreads();

        half8 af = *(const half8*)&A_lds[w * 16 + lr][lk * 8];
        #pragma unroll
        for (int ct = 0; ct < 4; ++ct) {
            half8 bf8 = *(const half8*)&B_lds[ct * 16 + lr][lk * 8];
            acc[ct] = __builtin_amdgcn_mfma_f32_16x16x32_f16(af, bf8,
                                                             acc[ct], 0, 0, 0);
        }
        __syncthreads();
    }

    // epilogue: D row = w*16 + lk*4 + i, col = n0 + ct*16 + lr
    #pragma unroll
    for (int ct = 0; ct < 4; ++ct) {
        const int col = n0 + ct * 16 + lr;
        if (col < G4) {
            const int pc = (col % 600) * 2 + (col >= 600);
            const float bv = bias[col];
            #pragma unroll
            for (int i = 0; i < 4; ++i) {
                const int row = row0 + w * 16 + lk * 4 + i;
                xgp[(size_t)row * G4 + pc] = __float2half(acc[ct][i] + bv);
            }
        }
    }
}

// ---------------- K2: LSTM scan, wide loads + LDS-cached U, fused FC --------
// 128 blocks = 64 batches x 2 dirs, 704 threads, 140.4 KB dynamic LDS.
//   tid 0..599   : thread t owns gate-cols t and t+600; 300-k dot via
//                  NC LDS-cached uint4 chunks + (38-NC) streamed uint4
//                  (16B = 8 fp16). v_dot2_f32_f16 vs fp16 h (double-buffered).
//   tid 640..703 : project prev step's h (f32) through fp16 W2s, atomicAdd.
__global__ __launch_bounds__(NTH)
void k2_rnn(const int* __restrict__ seqlen,
            const uint4* __restrict__ Upk4f, const uint4* __restrict__ Upk4b,
            const __half* __restrict__ xgpf, const __half* __restrict__ xgpb,
            const float* __restrict__ Wfc, float* __restrict__ out)
{
    const int w   = blockIdx.x;
    const int dir = w & 1;
    const int b   = w >> 1;
    const int L   = seqlen[b];
    const uint4* __restrict__ Up   = dir ? Upk4b : Upk4f;
    const __half* __restrict__ xgp = dir ? xgpb  : xgpf;

    extern __shared__ __align__(16) char smem[];
    uint4*          Us   = (uint4*)smem;                       // [NC*1200]
    unsigned short* W2s  = (unsigned short*)(Us + NC * 1200);  // [300*64]
    float*          h32  = (float*)(W2s + 300 * 64);           // [2][304]
    unsigned short* h16  = (unsigned short*)(h32 + 2 * 304);   // [2][304]
    float2*         sfo  = (float2*)(h16 + 2 * 304);           // [300]

    const int t = threadIdx.x;
    for (int i = t; i < NC * 1200; i += NTH) Us[i] = Up[i];
    for (int i = t; i < HID * TAGS; i += NTH)
        W2s[i] = f2h_bits(Wfc[(size_t)dir * HID * TAGS + i]);
    for (int i = t; i < 2 * 304; i += NTH) {
        h32[i] = 0.f;
        h16[i] = 0;
    }
    __syncthreads();

    float c = 0.f;
    const int pcol = t - 640;     // proj col if >= 0

    for (int ti = 0; ti < L; ++ti) {
        const int tf = dir ? (L - 1 - ti) : ti;
        const int rb = ti & 1;

        float d0 = 0.f, d1 = 0.f;
        if (t < 600) {
            const unsigned xv =
                *(const unsigned*)(xgp + ((size_t)b * TT + tf) * G4 + 2 * t);
            d0 = h_bits2f((unsigned short)(xv & 0xFFFF));
            d1 = h_bits2f((unsigned short)(xv >> 16));
            const uint4* hq = (const uint4*)(h16 + rb * 304);
            // streamed chunks (kq = NC..37)
            const uint4* u0p = Up + (size_t)NC * G4 + t;
            const uint4* u1p = u0p + 600;
            #pragma unroll 8
            for (int kq = 0; kq < KQ - NC; ++kq) {
                uint4 u0 = u0p[(size_t)kq * G4];
                uint4 u1 = u1p[(size_t)kq * G4];
                uint4 hh = hq[NC + kq];
                d0 = fdot2f(u0.x, hh.x, d0);
                d0 = fdot2f(u0.y, hh.y, d0);
                d0 = fdot2f(u0.z, hh.z, d0);
                d0 = fdot2f(u0.w, hh.w, d0);
                d1 = fdot2f(u1.x, hh.x, d1);
                d1 = fdot2f(u1.y, hh.y, d1);
                d1 = fdot2f(u1.z, hh.z, d1);
                d1 = fdot2f(u1.w, hh.w, d1);
            }
            // LDS-cached chunks (kq = 0..NC-1)
            #pragma unroll
            for (int kq = 0; kq < NC; ++kq) {
                uint4 u0 = Us[kq * 1200 + t];
                uint4 u1 = Us[kq * 1200 + t + 600];
                uint4 hh = hq[kq];
                d0 = fdot2f(u0.x, hh.x, d0);
                d0 = fdot2f(u0.y, hh.y, d0);
                d0 = fdot2f(u0.z, hh.z, d0);
                d0 = fdot2f(u0.w, hh.w, d0);
                d1 = fdot2f(u1.x, hh.x, d1);
                d1 = fdot2f(u1.y, hh.y, d1);
                d1 = fdot2f(u1.z, hh.z, d1);
                d1 = fdot2f(u1.w, hh.w, d1);
            }
            if (t >= 300) sfo[t - 300] = make_float2(d0, d1);
        } else if (pcol >= 0 && ti > 0) {
            // project h of previous step (buffer rb), overlapped with dots
            const float* hs = h32 + rb * 304;
            float acc = 0.f;
            for (int j2 = 0; j2 < HID; j2 += 4) {
                f32x4 h4 = *(const f32x4*)&hs[j2];
                acc = fmaf(h4.x, h_bits2f(W2s[(j2 + 0) * 64 + pcol]), acc);
                acc = fmaf(h4.y, h_bits2f(W2s[(j2 + 1) * 64 + pcol]), acc);
                acc = fmaf(h4.z, h_bits2f(W2s[(j2 + 2) * 64 + pcol]), acc);
                acc = fmaf(h4.w, h_bits2f(W2s[(j2 + 3) * 64 + pcol]), acc);
            }
            const int rowp = dir ? (tf + 1) : (tf - 1);
            atomicAdd(out + ((size_t)b * TT + rowp) * TAGS + pcol, acc);
        }
        __syncthreads();
        if (t < 300) {
            float2 fo = sfo[t];
            float i_ = sigm(d0);
            float z  = tanh_fast(d1);
            float f_ = sigm(fo.x);
            float o_ = sigm(fo.y);
            c = fmaf(f_, c, i_ * z);
            float hn = o_ * tanh_fast(c);
            h32[(rb ^ 1) * 304 + t] = hn;
            h16[(rb ^ 1) * 304 + t] = f2h_bits(hn);
        }
        __syncthreads();
    }

    // final projection (h of step L-1 is in buffer L&1) + tail fill
    if (pcol >= 0) {
        const float* hs = h32 + (L & 1) * 304;
        float acc = 0.f;
        for (int j2 = 0; j2 < HID; j2 += 4) {
            f32x4 h4 = *(const f32x4*)&hs[j2];
            acc = fmaf(h4.x, h_bits2f(W2s[(j2 + 0) * 64 + pcol]), acc);
            acc = fmaf(h4.y, h_bits2f(W2s[(j2 + 1) * 64 + pcol]), acc);
            acc = fmaf(h4.z, h_bits2f(W2s[(j2 + 2) * 64 + pcol]), acc);
            acc = fmaf(h4.w, h_bits2f(W2s[(j2 + 3) * 64 + pcol]), acc);
        }
        if (dir == 0) {
            float* o = out + (size_t)b * TT * TAGS + pcol;
            for (int tt = L - 1; tt < TT; ++tt)
                atomicAdd(o + (size_t)tt * TAGS, acc);
        } else {
            atomicAdd(out + (size_t)b * TT * TAGS + pcol, acc);
        }
    }
}

extern "C" void kernel_launch(void* const* d_in, const int* in_sizes, int n_in,
                              void* d_out, int out_size, void* d_ws, size_t ws_size,
                              hipStream_t stream)
{
    const int*   tokens = (const int*)d_in[0];
    const int*   seqlen = (const int*)d_in[1];
    const float* emb    = (const float*)d_in[2];
    const float* Wf     = (const float*)d_in[3];
    const float* Uf     = (const float*)d_in[4];
    const float* bf     = (const float*)d_in[5];
    const float* Wb     = (const float*)d_in[6];
    const float* Ub     = (const float*)d_in[7];
    const float* bb     = (const float*)d_in[8];
    const float* Wfc    = (const float*)d_in[9];
    const float* bfc    = (const float*)d_in[10];
    float* out = (float*)d_out;

    // ws: xgpf | xgpb (fp16, packed) | Upk4f | Upk4b | Wht
    const size_t xg_elems = (size_t)MM * G4;
    const size_t up_elems = (size_t)KQ * G4;            // uint4 per dir
    const size_t wh_elems = (size_t)2 * WCOLS * WK;     // fp16
    const size_t need = xg_elems * 2 * sizeof(__half)
                      + 2 * up_elems * sizeof(uint4)
                      + wh_elems * sizeof(_Float16);
    if (ws_size < need) {
        hipMemsetAsync(d_out, 0, (size_t)out_size * sizeof(float), stream);
        return;
    }
    __half*   xgpf  = (__half*)d_ws;
    __half*   xgpb  = xgpf + xg_elems;
    uint4*    Upk4f = (uint4*)(xgpb + xg_elems);
    uint4*    Upk4b = Upk4f + up_elems;
    _Float16* Wht   = (_Float16*)(Upk4b + up_elems);

    hipLaunchKernelGGL(kU_pack, dim3((2 * KQ * G4 + 255) / 256), dim3(256),
                       0, stream, Uf, Ub, Upk4f, Upk4b);
    hipLaunchKernelGGL(kW_pack, dim3((int)(wh_elems / 256)), dim3(256),
                       0, stream, Wf, Wb, Wht);
    hipLaunchKernelGGL(k_init, dim3(MM * TAGS / 256), dim3(256), 0, stream,
                       out, bfc);
    dim3 g1(MM / 64, (G4 + 63) / 64, 2);
    hipLaunchKernelGGL(k1_xg, g1, dim3(256), 0, stream,
                       tokens, seqlen, emb, Wht, bf, bb, xgpf, xgpb);

    hipFuncSetAttribute((const void*)k2_rnn,
                        hipFuncAttributeMaxDynamicSharedMemorySize, SMEM2);
    hipLaunchKernelGGL(k2_rnn, dim3(2 * BB), dim3(NTH), SMEM2, stream,
                       seqlen, Upk4f, Upk4b, xgpf, xgpb, Wfc, out);
}

// Round 9
// 3297.540 us; speedup vs baseline: 7.9679x; 1.0191x over previous
//
#include <hip/hip_runtime.h>
#include <hip/hip_fp16.h>

typedef float f32x4 __attribute__((ext_vector_type(4)));
typedef _Float16 half8 __attribute__((ext_vector_type(8)));
typedef _Float16 h2_t __attribute__((ext_vector_type(2)));

#define EMB   300
#define HID   300
#define G4    1200
#define TAGS  64
#define BB    64
#define TT    512
#define MM    (BB*TT)
#define KQ    38        // uint4 (8 fp16) k-chunks: 304 k (300 + 4 pad)
#define NC    6         // k-chunks of U cached in LDS
#define NTH   704
#define WCOLS 1216      // padded col count of Wht
#define WK    320       // padded k of Wht
// k2 dynamic LDS: Us | W2s | h32 | h16
#define SMEM2 (NC*1200*16 + 300*64*2 + 2*304*4 + 2*304*2)

__device__ __forceinline__ float sigm(float x) {
    return 1.0f / (1.0f + __expf(-x));
}
__device__ __forceinline__ float tanh_fast(float x) {
    float e = __expf(-2.0f * fabsf(x));
    float r = (1.0f - e) / (1.0f + e);
    return copysignf(r, x);
}
__device__ __forceinline__ float fdot2f(unsigned u, unsigned h, float acc) {
#if __has_builtin(__builtin_amdgcn_fdot2)
    return __builtin_amdgcn_fdot2(__builtin_bit_cast(h2_t, u),
                                  __builtin_bit_cast(h2_t, h), acc, false);
#else
    h2_t a = __builtin_bit_cast(h2_t, u), b = __builtin_bit_cast(h2_t, h);
    acc = fmaf((float)a.x, (float)b.x, acc);
    return fmaf((float)a.y, (float)b.y, acc);
#endif
}
__device__ __forceinline__ unsigned short f2h_bits(float f) {
    _Float16 h = (_Float16)f;
    return __builtin_bit_cast(unsigned short, h);
}
__device__ __forceinline__ float h_bits2f(unsigned short s) {
    return (float)__builtin_bit_cast(_Float16, s);
}

// ---------------- kW: W -> fp16, transposed + padded: Wht[dir][col][k] ------
__global__ __launch_bounds__(256)
void kW_pack(const float* __restrict__ Wf, const float* __restrict__ Wb,
             _Float16* __restrict__ Wht)
{
    const int idx = blockIdx.x * 256 + threadIdx.x;   // < 2*1216*320
    const int dir = idx / (WCOLS * WK);
    const int rem = idx % (WCOLS * WK);
    const int col = rem / WK;
    const int k   = rem % WK;
    const float* __restrict__ W = dir ? Wb : Wf;
    float v = (col < G4 && k < HID) ? W[(size_t)k * G4 + col] : 0.f;
    Wht[idx] = (_Float16)v;
}

// ---------------- kU: pack U -> fp16 [dir][kq][cp] uint4, permuted cols -----
// packed col cp: slot = cp/600, w = cp%600, u = w>>1, p = w&1
//   -> orig col = slot*600 + p*300 + u
// So thread t (unit u=t>>1, parity p=t&1) reads cp = t (slot0) and t+600
// (slot1): even threads get (i,cc) cols, odd get (f,o) cols, contiguous.
__global__ __launch_bounds__(256)
void kU_pack(const float* __restrict__ Uf, const float* __restrict__ Ub,
             uint4* __restrict__ Upk4f, uint4* __restrict__ Upk4b)
{
    const int idx = blockIdx.x * 256 + threadIdx.x;
    if (idx >= 2 * KQ * G4) return;
    const int dir = idx / (KQ * G4);
    const int rem = idx % (KQ * G4);
    const int kq  = rem / G4;
    const int cp  = rem % G4;
    const int slot = cp / 600;
    const int wwp  = cp % 600;
    const int col  = slot * 600 + (wwp & 1) * 300 + (wwp >> 1);
    const float* __restrict__ U = dir ? Ub : Uf;
    float v[8];
    #pragma unroll
    for (int u = 0; u < 8; ++u) {
        const int k = 8 * kq + u;
        v[u] = (k < HID) ? U[(size_t)k * G4 + col] : 0.f;
    }
    __half2 p0 = __floats2half2_rn(v[0], v[1]);
    __half2 p1 = __floats2half2_rn(v[2], v[3]);
    __half2 p2 = __floats2half2_rn(v[4], v[5]);
    __half2 p3 = __floats2half2_rn(v[6], v[7]);
    uint4 o;
    o.x = *(unsigned*)&p0; o.y = *(unsigned*)&p1;
    o.z = *(unsigned*)&p2; o.w = *(unsigned*)&p3;
    (dir ? Upk4b : Upk4f)[rem] = o;
}

// ---------------- k_init: out[r][c] = bfc[c] --------------------------------
__global__ __launch_bounds__(256)
void k_init(float* __restrict__ out, const float* __restrict__ bfc)
{
    const size_t i = (size_t)blockIdx.x * 256 + threadIdx.x;
    out[i] = bfc[i & 63];
}

// ---------------- K1: xg = emb[tokens] @ W + bias via MFMA fp16 -------------
// grid (512, 19, 2), 256 thr = 4 waves. 64x64 tile, k-loop 10x32 (padded 320).
// Output packed unit-major: orig col c -> pc = 4*(c%600%300) + 2*(c%600/300)
// + (c/600), i.e. unit u occupies halfs [4u,4u+4) as (i,cc,f,o).
__global__ __launch_bounds__(256)
void k1_xg(const int* __restrict__ tokens, const int* __restrict__ seqlen,
           const float* __restrict__ emb, const _Float16* __restrict__ Wht,
           const float* __restrict__ bf, const float* __restrict__ bb,
           __half* __restrict__ xgpf, __half* __restrict__ xgpb)
{
    const int z = blockIdx.z;
    const _Float16* __restrict__ Wh = Wht + (size_t)z * WCOLS * WK;
    const float* __restrict__ bias  = z ? bb : bf;
    __half* __restrict__ xgp        = z ? xgpb : xgpf;

    const int row0 = blockIdx.x * 64;
    const int b    = row0 >> 9;
    const int t0   = row0 & 511;
    if (t0 >= seqlen[b]) return;       // strip fully masked -> never consumed

    const int n0 = blockIdx.y * 64;

    __shared__ int toks[64];
    __shared__ __align__(16) _Float16 A_lds[64][40];
    __shared__ __align__(16) _Float16 B_lds[64][40];

    const int tid = threadIdx.x;
    if (tid < 64) toks[tid] = tokens[row0 + tid];
    __syncthreads();

    const int r = tid >> 2, q = tid & 3;     // staging identity
    const int lane = tid & 63, w = tid >> 6;
    const int lr = lane & 15, lk = lane >> 4;

    f32x4 acc[4];
    #pragma unroll
    for (int ct = 0; ct < 4; ++ct) acc[ct] = (f32x4){0.f, 0.f, 0.f, 0.f};

    const float* er = emb + (size_t)toks[r] * EMB;

    for (int kc = 0; kc < WK; kc += 32) {
        {
            half8 av;
            #pragma unroll
            for (int u = 0; u < 8; ++u) {
                const int k = kc + q * 8 + u;
                av[u] = (k < EMB) ? (_Float16)er[k] : (_Float16)0.f;
            }
            *(half8*)&A_lds[r][q * 8] = av;
        }
        *(half8*)&B_lds[r][q * 8] =
            *(const half8*)(Wh + (size_t)(n0 + r) * WK + kc + q * 8);
        __syncthreads();

        half8 af = *(const half8*)&A_lds[w * 16 + lr][lk * 8];
        #pragma unroll
        for (int ct = 0; ct < 4; ++ct) {
            half8 bf8 = *(const half8*)&B_lds[ct * 16 + lr][lk * 8];
            acc[ct] = __builtin_amdgcn_mfma_f32_16x16x32_f16(af, bf8,
                                                             acc[ct], 0, 0, 0);
        }
        __syncthreads();
    }

    // epilogue: D row = w*16 + lk*4 + i, col = n0 + ct*16 + lr
    #pragma unroll
    for (int ct = 0; ct < 4; ++ct) {
        const int col = n0 + ct * 16 + lr;
        if (col < G4) {
            const int rem  = col % 600;
            const int pc   = 4 * (rem % 300) + 2 * (rem / 300) + (col / 600);
            const float bv = bias[col];
            #pragma unroll
            for (int i = 0; i < 4; ++i) {
                const int row = row0 + w * 16 + lk * 4 + i;
                xgp[(size_t)row * G4 + pc] = __float2half(acc[ct][i] + bv);
            }
        }
    }
}

// ---------------- K2: LSTM scan, single barrier/step, fused FC --------------
// 128 blocks = 64 batches x 2 dirs, 704 threads, 157.2 KB dynamic LDS.
//   tid 0..599   : thread t owns packed cols t, t+600 (unit u=t>>1; even:
//                  i,cc dots; odd: f,o dots). 6 LDS-cached + 32 streamed
//                  uint4 chunks per col. Pair exchange via __shfl_xor(1);
//                  even thread runs the nonlinearity (c in reg) and writes
//                  h (double-buffered f32+fp16). ONE barrier per step.
//   tid 640..703 : project prev step's h through fp16 W2s, atomicAdd into
//                  bfc-initialized out; overlapped with dot phase.
__global__ __launch_bounds__(NTH)
void k2_rnn(const int* __restrict__ seqlen,
            const uint4* __restrict__ Upk4f, const uint4* __restrict__ Upk4b,
            const __half* __restrict__ xgpf, const __half* __restrict__ xgpb,
            const float* __restrict__ Wfc, float* __restrict__ out)
{
    const int w   = blockIdx.x;
    const int dir = w & 1;
    const int b   = w >> 1;
    const int L   = seqlen[b];
    const uint4* __restrict__ Up   = dir ? Upk4b : Upk4f;
    const __half* __restrict__ xgp = dir ? xgpb  : xgpf;

    extern __shared__ __align__(16) char smem[];
    uint4*          Us   = (uint4*)smem;                       // [NC*1200]
    unsigned short* W2s  = (unsigned short*)(Us + NC * 1200);  // [300*64]
    float*          h32  = (float*)(W2s + 300 * 64);           // [2][304]
    unsigned short* h16  = (unsigned short*)(h32 + 2 * 304);   // [2][304]

    const int t = threadIdx.x;
    for (int i = t; i < NC * 1200; i += NTH) Us[i] = Up[i];
    for (int i = t; i < HID * TAGS; i += NTH)
        W2s[i] = f2h_bits(Wfc[(size_t)dir * HID * TAGS + i]);
    for (int i = t; i < 2 * 304; i += NTH) {
        h32[i] = 0.f;
        h16[i] = 0;
    }
    __syncthreads();

    float c = 0.f;
    const int u    = t >> 1;      // unit (dot threads)
    const int pcol = t - 640;     // proj col if >= 0

    for (int ti = 0; ti < L; ++ti) {
        const int tf = dir ? (L - 1 - ti) : ti;
        const int rb = ti & 1;

        if (t < 600) {
            const unsigned xv =
                *(const unsigned*)(xgp + ((size_t)b * TT + tf) * G4 + 2 * t);
            float d0 = h_bits2f((unsigned short)(xv & 0xFFFF));
            float d1 = h_bits2f((unsigned short)(xv >> 16));
            const uint4* hq = (const uint4*)(h16 + rb * 304);
            // streamed chunks (kq = NC..37)
            const uint4* u0p = Up + (size_t)NC * G4 + t;
            const uint4* u1p = u0p + 600;
            #pragma unroll 8
            for (int kq = 0; kq < KQ - NC; ++kq) {
                uint4 u0 = u0p[(size_t)kq * G4];
                uint4 u1 = u1p[(size_t)kq * G4];
                uint4 hh = hq[NC + kq];
                d0 = fdot2f(u0.x, hh.x, d0);
                d0 = fdot2f(u0.y, hh.y, d0);
                d0 = fdot2f(u0.z, hh.z, d0);
                d0 = fdot2f(u0.w, hh.w, d0);
                d1 = fdot2f(u1.x, hh.x, d1);
                d1 = fdot2f(u1.y, hh.y, d1);
                d1 = fdot2f(u1.z, hh.z, d1);
                d1 = fdot2f(u1.w, hh.w, d1);
            }
            // LDS-cached chunks (kq = 0..NC-1)
            #pragma unroll
            for (int kq = 0; kq < NC; ++kq) {
                uint4 u0 = Us[kq * 1200 + t];
                uint4 u1 = Us[kq * 1200 + t + 600];
                uint4 hh = hq[kq];
                d0 = fdot2f(u0.x, hh.x, d0);
                d0 = fdot2f(u0.y, hh.y, d0);
                d0 = fdot2f(u0.z, hh.z, d0);
                d0 = fdot2f(u0.w, hh.w, d0);
                d1 = fdot2f(u1.x, hh.x, d1);
                d1 = fdot2f(u1.y, hh.y, d1);
                d1 = fdot2f(u1.z, hh.z, d1);
                d1 = fdot2f(u1.w, hh.w, d1);
            }
            // pair exchange: even thread (i,cc) gets odd's (f,o)
            const float fd0 = __shfl_xor(d0, 1);
            const float fd1 = __shfl_xor(d1, 1);
            if (!(t & 1)) {
                const float i_ = sigm(d0);
                const float z_ = tanh_fast(d1);
                const float f_ = sigm(fd0);
                const float o_ = sigm(fd1);
                c = fmaf(f_, c, i_ * z_);
                const float hn = o_ * tanh_fast(c);
                h32[(rb ^ 1) * 304 + u] = hn;
                h16[(rb ^ 1) * 304 + u] = f2h_bits(hn);
            }
        } else if (pcol >= 0 && ti > 0) {
            // project h of previous step (buffer rb), overlapped with dots
            const float* hs = h32 + rb * 304;
            float acc = 0.f;
            for (int j2 = 0; j2 < HID; j2 += 4) {
                f32x4 h4 = *(const f32x4*)&hs[j2];
                acc = fmaf(h4.x, h_bits2f(W2s[(j2 + 0) * 64 + pcol]), acc);
                acc = fmaf(h4.y, h_bits2f(W2s[(j2 + 1) * 64 + pcol]), acc);
                acc = fmaf(h4.z, h_bits2f(W2s[(j2 + 2) * 64 + pcol]), acc);
                acc = fmaf(h4.w, h_bits2f(W2s[(j2 + 3) * 64 + pcol]), acc);
            }
            const int rowp = dir ? (tf + 1) : (tf - 1);
            atomicAdd(out + ((size_t)b * TT + rowp) * TAGS + pcol, acc);
        }
        __syncthreads();   // the ONE barrier: h(ti) published for step ti+1
    }

    // final projection (h of step L-1 is in buffer L&1) + tail fill
    if (pcol >= 0) {
        const float* hs = h32 + (L & 1) * 304;
        float acc = 0.f;
        for (int j2 = 0; j2 < HID; j2 += 4) {
            f32x4 h4 = *(const f32x4*)&hs[j2];
            acc = fmaf(h4.x, h_bits2f(W2s[(j2 + 0) * 64 + pcol]), acc);
            acc = fmaf(h4.y, h_bits2f(W2s[(j2 + 1) * 64 + pcol]), acc);
            acc = fmaf(h4.z, h_bits2f(W2s[(j2 + 2) * 64 + pcol]), acc);
            acc = fmaf(h4.w, h_bits2f(W2s[(j2 + 3) * 64 + pcol]), acc);
        }
        if (dir == 0) {
            float* o = out + (size_t)b * TT * TAGS + pcol;
            for (int tt = L - 1; tt < TT; ++tt)
                atomicAdd(o + (size_t)tt * TAGS, acc);
        } else {
            atomicAdd(out + (size_t)b * TT * TAGS + pcol, acc);
        }
    }
}

extern "C" void kernel_launch(void* const* d_in, const int* in_sizes, int n_in,
                              void* d_out, int out_size, void* d_ws, size_t ws_size,
                              hipStream_t stream)
{
    const int*   tokens = (const int*)d_in[0];
    const int*   seqlen = (const int*)d_in[1];
    const float* emb    = (const float*)d_in[2];
    const float* Wf     = (const float*)d_in[3];
    const float* Uf     = (const float*)d_in[4];
    const float* bf     = (const float*)d_in[5];
    const float* Wb     = (const float*)d_in[6];
    const float* Ub     = (const float*)d_in[7];
    const float* bb     = (const float*)d_in[8];
    const float* Wfc    = (const float*)d_in[9];
    const float* bfc    = (const float*)d_in[10];
    float* out = (float*)d_out;

    // ws: xgpf | xgpb (fp16, packed) | Upk4f | Upk4b | Wht
    const size_t xg_elems = (size_t)MM * G4;
    const size_t up_elems = (size_t)KQ * G4;            // uint4 per dir
    const size_t wh_elems = (size_t)2 * WCOLS * WK;     // fp16
    const size_t need = xg_elems * 2 * sizeof(__half)
                      + 2 * up_elems * sizeof(uint4)
                      + wh_elems * sizeof(_Float16);
    if (ws_size < need) {
        hipMemsetAsync(d_out, 0, (size_t)out_size * sizeof(float), stream);
        return;
    }
    __half*   xgpf  = (__half*)d_ws;
    __half*   xgpb  = xgpf + xg_elems;
    uint4*    Upk4f = (uint4*)(xgpb + xg_elems);
    uint4*    Upk4b = Upk4f + up_elems;
    _Float16* Wht   = (_Float16*)(Upk4b + up_elems);

    hipLaunchKernelGGL(kU_pack, dim3((2 * KQ * G4 + 255) / 256), dim3(256),
                       0, stream, Uf, Ub, Upk4f, Upk4b);
    hipLaunchKernelGGL(kW_pack, dim3((int)(wh_elems / 256)), dim3(256),
                       0, stream, Wf, Wb, Wht);
    hipLaunchKernelGGL(k_init, dim3(MM * TAGS / 256), dim3(256), 0, stream,
                       out, bfc);
    dim3 g1(MM / 64, (G4 + 63) / 64, 2);
    hipLaunchKernelGGL(k1_xg, g1, dim3(256), 0, stream,
                       tokens, seqlen, emb, Wht, bf, bb, xgpf, xgpb);

    hipFuncSetAttribute((const void*)k2_rnn,
                        hipFuncAttributeMaxDynamicSharedMemorySize, SMEM2);
    hipLaunchKernelGGL(k2_rnn, dim3(2 * BB), dim3(NTH), SMEM2, stream,
                       seqlen, Upk4f, Upk4b, xgpf, xgpb, Wfc, out);
}